// Round 1
// baseline (474.402 us; speedup 1.0000x reference)
//
#include <hip/hip_runtime.h>
#include <math.h>

#define D 128
#define LLEN 200
#define SLEN 50
#define CH 64
#define ESTR 132          // floats/row: 528B = 16B-aligned rows; b128 quad = (row+col4)&7 -> conflict-free
#define NEG (-1e9f)

__device__ __forceinline__ float wave_red_sum(float v) {
#pragma unroll
  for (int m = 32; m >= 1; m >>= 1) v += __shfl_xor(v, m, 64);
  return v;
}
// 256-thread block sum; ALL threads must call.
__device__ __forceinline__ float block_sum(float v, float* red) {
  v = wave_red_sum(v);
  if ((threadIdx.x & 63) == 0) red[threadIdx.x >> 6] = v;
  __syncthreads();
  v = red[0] + red[1] + red[2] + red[3];
  __syncthreads();
  return v;
}

__global__ void __launch_bounds__(256, 4) din_kernel(
    const float* __restrict__ user_table, const float* __restrict__ item_table,
    const float* __restrict__ W1, const float* __restrict__ b1,
    const float* __restrict__ W2, const float* __restrict__ b2,
    const int* __restrict__ user_inputs, const int* __restrict__ L_inputs,
    const int* __restrict__ S_inputs, const int* __restrict__ item_inputs,
    float* __restrict__ out) {
  __shared__ float ebuf[CH * ESTR];   // 33,792B staged rows; also prolog/epilog scratch
  __shared__ float hspart[4 * 65];    // per-wave hs partials, stride 65 (conflict-free)
  __shared__ float w_sh[CH];          // unnormalized softmax weights for current chunk
  __shared__ int rows1[LLEN];
  __shared__ int rowsS[SLEN];
  __shared__ float upart_sh[16];
  __shared__ float red_sh[4];

  const int b = blockIdx.x;
  const int tid = threadIdx.x;
  const int lane = tid & 63;
  const int w = __builtin_amdgcn_readfirstlane(tid >> 6);  // wave id -> SGPR (W1 s_load)
  const int col4 = tid & 31;          // float4 column for weighted sum (d = 4*col4..+3)
  const int grp  = tid >> 5;          // row group 0..7 for weighted sum
  const float4* it4 = reinterpret_cast<const float4*>(item_table);

  // ---- prolog: indices + user embedding (u_sh/part alias into ebuf) ----
  float* u_sh = &ebuf[0];
  float* part = &ebuf[128];
  if (tid < D) u_sh[tid] = user_table[(size_t)user_inputs[b] * D + tid];
  if (tid < LLEN) rows1[tid] = L_inputs[(size_t)b * LLEN + tid];
  if (tid < SLEN) rowsS[tid] = S_inputs[(size_t)b * SLEN + tid];
  __syncthreads();

  // issue chunk-0 gathers early: latency hides under the u@W1 prolog MLP
  auto load_chunk = [&](float4 (&v)[8], int c) {
    const int base = c * CH;
    const int cnt = (base + CH <= LLEN) ? CH : (LLEN - base);
    const int nslot = cnt * 32;
#pragma unroll
    for (int it = 0; it < 8; ++it) {
      int s = tid + it * 256;
      if (s < nslot) {
        int gid = rows1[base + (s >> 5)];
        if (gid < 0) gid = 0;
        v[it] = it4[(size_t)gid * 32 + (s & 31)];
      }
    }
  };
  float4 v[8];
  load_chunk(v, 0);

  // u_part[j] = b1[j] + u @ W1[0:128,:]
  {
    int j = tid & 15, g = tid >> 4;
    float p = 0.f;
#pragma unroll
    for (int t = 0; t < 8; ++t) {
      int d = g * 8 + t;
      p = fmaf(u_sh[d], W1[d * 16 + j], p);
    }
    part[tid] = p;
  }
  __syncthreads();
  if (tid < 16) {
    float s = b1[tid];
#pragma unroll
    for (int g = 0; g < 16; ++g) s += part[g * 16 + tid];
    upart_sh[tid] = s;
  }
  __syncthreads();

  const float b2v = b2[0];
  const float w2a = W2[4 * w + 0], w2b = W2[4 * w + 1];
  const float w2c = W2[4 * w + 2], w2d = W2[4 * w + 3];

  float pacc = 0.f;                       // per-thread sum of unnormalized weights
  float4 uacc = make_float4(0.f, 0.f, 0.f, 0.f);  // partial of sum_l p_l * e_l[4*col4..+3]

  // ================= stage 1: 4 chunks {64,64,64,8} =================
  for (int c = 0; c < 4; ++c) {
    const int base = c * CH;
    const int cnt = (base + CH <= LLEN) ? CH : (LLEN - base);
    const int nslot = cnt * 32;

    // -- stage prefetched rows: single ds_write_b128 per float4 --
#pragma unroll
    for (int it = 0; it < 8; ++it) {
      int s = tid + it * 256;
      if (s < nslot)
        reinterpret_cast<float4*>(&ebuf[(s >> 5) * ESTR])[s & 31] = v[it];
    }
    __syncthreads();

    // -- matvec: wave w computes j in [4w,4w+4) for item=lane; b128 row reads --
    if (lane < cnt) {
      float a0 = 0.f, a1 = 0.f, a2 = 0.f, a3 = 0.f;
      const float4* er4 = reinterpret_cast<const float4*>(&ebuf[lane * ESTR]);
      const float* wc = &W1[(size_t)D * 16 + 4 * w];  // rows 128.., cols 4w.. (wave-uniform -> s_load)
#pragma unroll 8
      for (int k = 0; k < 32; ++k) {
        float4 e = er4[k];
        const float* wr = wc + k * 64;
        a0 = fmaf(e.x, wr[0],  a0); a1 = fmaf(e.x, wr[1],  a1);
        a2 = fmaf(e.x, wr[2],  a2); a3 = fmaf(e.x, wr[3],  a3);
        a0 = fmaf(e.y, wr[16], a0); a1 = fmaf(e.y, wr[17], a1);
        a2 = fmaf(e.y, wr[18], a2); a3 = fmaf(e.y, wr[19], a3);
        a0 = fmaf(e.z, wr[32], a0); a1 = fmaf(e.z, wr[33], a1);
        a2 = fmaf(e.z, wr[34], a2); a3 = fmaf(e.z, wr[35], a3);
        a0 = fmaf(e.w, wr[48], a0); a1 = fmaf(e.w, wr[49], a1);
        a2 = fmaf(e.w, wr[50], a2); a3 = fmaf(e.w, wr[51], a3);
      }
      float hs = fmaxf(upart_sh[4 * w + 0] + a0, 0.f) * w2a;
      hs = fmaf(fmaxf(upart_sh[4 * w + 1] + a1, 0.f), w2b, hs);
      hs = fmaf(fmaxf(upart_sh[4 * w + 2] + a2, 0.f), w2c, hs);
      hs = fmaf(fmaxf(upart_sh[4 * w + 3] + a3, 0.f), w2d, hs);
      hspart[w * 65 + lane] = hs;
    }
    __syncthreads();

    // -- finalize logits -> unnormalized weights (no max-shift: |lg| << 80) --
    if (tid < cnt) {
      float lg = hspart[tid] + hspart[65 + tid] + hspart[130 + tid] +
                 hspart[195 + tid] + b2v;
      float p = (rows1[base + tid] >= 0) ? expf(lg) : 0.f;
      w_sh[tid] = p;
      pacc += p;
    }
    __syncthreads();

    // -- prefetch next chunk's gathers: latency hides under weighted accum --
    if (c < 3) load_chunk(v, c + 1);

    // -- weighted accumulate: b128 reads, 8 row-groups x 32 float4-columns --
    for (int l = grp; l < cnt; l += 8) {
      float wl = w_sh[l];
      const float4 e = reinterpret_cast<const float4*>(&ebuf[l * ESTR])[col4];
      uacc.x = fmaf(wl, e.x, uacc.x);
      uacc.y = fmaf(wl, e.y, uacc.y);
      uacc.z = fmaf(wl, e.z, uacc.z);
      uacc.w = fmaf(wl, e.w, uacc.w);
    }
    __syncthreads();  // ebuf/w_sh reused next chunk
  }

  // -- prefetch S-row gathers: latency hides under u_long epilogue --
  float4 v2[7];
#pragma unroll
  for (int it = 0; it < 7; ++it) {
    int s = tid + it * 256;
    if (s < SLEN * 32) {
      int gid = rowsS[s >> 5];
      if (gid < 0) gid = 0;
      v2[it] = it4[(size_t)gid * 32 + (s & 31)];
    }
  }

  // ---- u_long: reduce uacc (scratch = dead rows 52..63), normalize -> ebuf row 0 ----
  const float invS1 = 1.f / block_sum(pacc, red_sh);
  float* scr = &ebuf[52 * ESTR];  // 1024-float scratch; stage rows <= 50 end at float 6728 < 6864
  reinterpret_cast<float4*>(scr)[tid] = uacc;   // scr[grp*128 + d]
  __syncthreads();
  if (tid < D) {
    float s = 0.f;
#pragma unroll
    for (int g = 0; g < 8; ++g) s += scr[g * 128 + tid];
    ebuf[tid] = s * invS1;  // row 0 = u_long (stage-2 item 0)
  }
  // S rows -> ebuf rows 1..50 (disjoint from row 0 and scr: same barrier interval OK)
#pragma unroll
  for (int it = 0; it < 7; ++it) {
    int s = tid + it * 256;
    if (s < SLEN * 32)
      reinterpret_cast<float4*>(&ebuf[((s >> 5) + 1) * ESTR])[s & 31] = v2[it];
  }
  __syncthreads();

  // ================= stage 2: [u_long] + 50 S rows =================
  const int n2 = 1 + SLEN;  // 51
  if (lane < n2) {
    float a0 = 0.f, a1 = 0.f, a2 = 0.f, a3 = 0.f;
    const float4* er4 = reinterpret_cast<const float4*>(&ebuf[lane * ESTR]);
    const float* wc = &W1[(size_t)D * 16 + 4 * w];
#pragma unroll 8
    for (int k = 0; k < 32; ++k) {
      float4 e = er4[k];
      const float* wr = wc + k * 64;
      a0 = fmaf(e.x, wr[0],  a0); a1 = fmaf(e.x, wr[1],  a1);
      a2 = fmaf(e.x, wr[2],  a2); a3 = fmaf(e.x, wr[3],  a3);
      a0 = fmaf(e.y, wr[16], a0); a1 = fmaf(e.y, wr[17], a1);
      a2 = fmaf(e.y, wr[18], a2); a3 = fmaf(e.y, wr[19], a3);
      a0 = fmaf(e.z, wr[32], a0); a1 = fmaf(e.z, wr[33], a1);
      a2 = fmaf(e.z, wr[34], a2); a3 = fmaf(e.z, wr[35], a3);
      a0 = fmaf(e.w, wr[48], a0); a1 = fmaf(e.w, wr[49], a1);
      a2 = fmaf(e.w, wr[50], a2); a3 = fmaf(e.w, wr[51], a3);
    }
    float hs = fmaxf(upart_sh[4 * w + 0] + a0, 0.f) * w2a;
    hs = fmaf(fmaxf(upart_sh[4 * w + 1] + a1, 0.f), w2b, hs);
    hs = fmaf(fmaxf(upart_sh[4 * w + 2] + a2, 0.f), w2c, hs);
    hs = fmaf(fmaxf(upart_sh[4 * w + 3] + a3, 0.f), w2d, hs);
    hspart[w * 65 + lane] = hs;
  }
  __syncthreads();

  float p2 = 0.f;
  if (tid < n2) {
    float lg = hspart[tid] + hspart[65 + tid] + hspart[130 + tid] +
               hspart[195 + tid] + b2v;
    bool valid = (tid == 0) || (rowsS[tid - 1] >= 0);
    p2 = valid ? expf(lg) : 0.f;
    w_sh[tid] = p2;
  }
  const float invS2 = 1.f / block_sum(p2, red_sh);  // barrier publishes w_sh

  float4 uacc2 = make_float4(0.f, 0.f, 0.f, 0.f);
  for (int l = grp; l < n2; l += 8) {
    float wl = w_sh[l];
    const float4 e = reinterpret_cast<const float4*>(&ebuf[l * ESTR])[col4];
    uacc2.x = fmaf(wl, e.x, uacc2.x);
    uacc2.y = fmaf(wl, e.y, uacc2.y);
    uacc2.z = fmaf(wl, e.z, uacc2.z);
    uacc2.w = fmaf(wl, e.w, uacc2.w);
  }
  reinterpret_cast<float4*>(scr)[tid] = uacc2;  // rows 52..63 untouched by stage-2 rows 0..50
  __syncthreads();

  // ---- score = dot(user_hybrid, item_emb) ----
  float sv = 0.f;
  if (tid < D) {
    float s = 0.f;
#pragma unroll
    for (int g = 0; g < 8; ++g) s += scr[g * 128 + tid];
    float uh = s * invS2;
    sv = uh * item_table[(size_t)item_inputs[b] * D + tid];
  }
  float tot = block_sum(sv, red_sh);
  if (tid == 0) out[b] = tot;
}

extern "C" void kernel_launch(void* const* d_in, const int* in_sizes, int n_in,
                              void* d_out, int out_size, void* d_ws, size_t ws_size,
                              hipStream_t stream) {
  const float* user_table = (const float*)d_in[0];
  const float* item_table = (const float*)d_in[1];
  const float* W1 = (const float*)d_in[2];
  const float* b1 = (const float*)d_in[3];
  const float* W2 = (const float*)d_in[4];
  const float* b2 = (const float*)d_in[5];
  const int* user_inputs = (const int*)d_in[6];
  const int* L_inputs = (const int*)d_in[7];
  const int* S_inputs = (const int*)d_in[8];
  const int* item_inputs = (const int*)d_in[9];
  float* out = (float*)d_out;

  const int B = in_sizes[6];  // 4096
  din_kernel<<<B, 256, 0, stream>>>(user_table, item_table, W1, b1, W2, b2,
                                    user_inputs, L_inputs, S_inputs, item_inputs,
                                    out);
}

// Round 2
// 269.539 us; speedup vs baseline: 1.7600x; 1.7600x over previous
//
#include <hip/hip_runtime.h>
#include <math.h>

#define D 128
#define LLEN 200
#define SLEN 50
#define CH 64
#define ESTR 132  // floats/row: 528B, 16B-aligned; b128 quad = (33r+c4)&7 = (r+c4)&7 -> conflict-free
#define NEG (-1e9f)

__device__ __forceinline__ float wave_red_sum(float v) {
#pragma unroll
  for (int m = 32; m >= 1; m >>= 1) v += __shfl_xor(v, m, 64);
  return v;
}
// 256-thread block sum; ALL threads must call.
__device__ __forceinline__ float block_sum(float v, float* red) {
  v = wave_red_sum(v);
  if ((threadIdx.x & 63) == 0) red[threadIdx.x >> 6] = v;
  __syncthreads();
  v = red[0] + red[1] + red[2] + red[3];
  __syncthreads();
  return v;
}

// Gather one float4 slot of an L-chunk: slot s = tid + IT; row = BASE + s/32.
// Named-scalar destination (p0..p7) => guaranteed VGPRs, no SROA hazard.
#define GATHER_L(dst, IT, BASE)                          \
  do {                                                   \
    int s_ = tid + (IT);                                 \
    int gid_ = rows1[(BASE) + (s_ >> 5)];                \
    if (gid_ < 0) gid_ = 0;                              \
    dst = it4[(size_t)gid_ * 32 + (s_ & 31)];            \
  } while (0)

#define GATHER_S(dst, IT)                                \
  do {                                                   \
    int s_ = tid + (IT);                                 \
    int gid_ = rowsS[s_ >> 5];                           \
    if (gid_ < 0) gid_ = 0;                              \
    dst = it4[(size_t)gid_ * 32 + (s_ & 31)];            \
  } while (0)

// Store one prefetched float4 to staged row (s/32), col (s&31): single ds_write_b128.
#define STORE_L(src, IT)                                                    \
  do {                                                                      \
    int s_ = tid + (IT);                                                    \
    reinterpret_cast<float4*>(&ebuf[(s_ >> 5) * ESTR])[s_ & 31] = src;      \
  } while (0)

// Stage-2 rows land at ebuf rows 1..50.
#define STORE_S(src, IT)                                                    \
  do {                                                                      \
    int s_ = tid + (IT);                                                    \
    reinterpret_cast<float4*>(&ebuf[((s_ >> 5) + 1) * ESTR])[s_ & 31] = src; \
  } while (0)

// Wave w computes j in [4w,4w+4) for item=lane; full row read as 32 ds_read_b128.
#define MATVEC_PHASE(CNT)                                                   \
  if (lane < (CNT)) {                                                       \
    float a0 = 0.f, a1 = 0.f, a2 = 0.f, a3 = 0.f;                           \
    const float4* er4 = reinterpret_cast<const float4*>(&ebuf[lane * ESTR]);\
    const float* wc = &W1[(size_t)D * 16 + 4 * w];                          \
    _Pragma("unroll 8")                                                     \
    for (int k = 0; k < 32; ++k) {                                          \
      float4 e = er4[k];                                                    \
      const float* wr = wc + k * 64; /* wave-uniform -> s_load */           \
      a0 = fmaf(e.x, wr[0],  a0); a1 = fmaf(e.x, wr[1],  a1);               \
      a2 = fmaf(e.x, wr[2],  a2); a3 = fmaf(e.x, wr[3],  a3);               \
      a0 = fmaf(e.y, wr[16], a0); a1 = fmaf(e.y, wr[17], a1);               \
      a2 = fmaf(e.y, wr[18], a2); a3 = fmaf(e.y, wr[19], a3);               \
      a0 = fmaf(e.z, wr[32], a0); a1 = fmaf(e.z, wr[33], a1);               \
      a2 = fmaf(e.z, wr[34], a2); a3 = fmaf(e.z, wr[35], a3);               \
      a0 = fmaf(e.w, wr[48], a0); a1 = fmaf(e.w, wr[49], a1);               \
      a2 = fmaf(e.w, wr[50], a2); a3 = fmaf(e.w, wr[51], a3);               \
    }                                                                       \
    float hs = fmaxf(upart_sh[4 * w + 0] + a0, 0.f) * w2a;                  \
    hs = fmaf(fmaxf(upart_sh[4 * w + 1] + a1, 0.f), w2b, hs);               \
    hs = fmaf(fmaxf(upart_sh[4 * w + 2] + a2, 0.f), w2c, hs);               \
    hs = fmaf(fmaxf(upart_sh[4 * w + 3] + a3, 0.f), w2d, hs);               \
    hspart[w * 65 + lane] = hs;                                             \
  }

__global__ void __launch_bounds__(256, 4) din_kernel(
    const float* __restrict__ user_table, const float* __restrict__ item_table,
    const float* __restrict__ W1, const float* __restrict__ b1,
    const float* __restrict__ W2, const float* __restrict__ b2,
    const int* __restrict__ user_inputs, const int* __restrict__ L_inputs,
    const int* __restrict__ S_inputs, const int* __restrict__ item_inputs,
    float* __restrict__ out) {
  __shared__ float ebuf[CH * ESTR];   // 33,792B staged rows; also prolog/epilog scratch
  __shared__ float hspart[4 * 65];    // per-wave hs partials, stride 65 (conflict-free)
  __shared__ float w_sh[CH];          // unnormalized softmax weights for current chunk
  __shared__ int rows1[LLEN];
  __shared__ int rowsS[SLEN];
  __shared__ float upart_sh[16];
  __shared__ float red_sh[4];

  const int b = blockIdx.x;
  const int tid = threadIdx.x;
  const int lane = tid & 63;
  const int w = __builtin_amdgcn_readfirstlane(tid >> 6);  // wave id -> SGPR
  const int col4 = tid & 31;          // float4 column for weighted sum
  const int grp  = tid >> 5;          // row group 0..7 for weighted sum
  const float4* it4 = reinterpret_cast<const float4*>(item_table);

  // ---- prolog: indices + user embedding (u_sh/part alias into ebuf) ----
  float* u_sh = &ebuf[0];
  float* part = &ebuf[128];
  if (tid < D) u_sh[tid] = user_table[(size_t)user_inputs[b] * D + tid];
  if (tid < LLEN) rows1[tid] = L_inputs[(size_t)b * LLEN + tid];
  if (tid < SLEN) rowsS[tid] = S_inputs[(size_t)b * SLEN + tid];
  __syncthreads();

  // prefetch chunk 0 (64 rows = 2048 slots, unconditional): hides under prolog MLP
  float4 p0, p1, p2, p3, p4, p5, p6, p7;
  GATHER_L(p0, 0,    0); GATHER_L(p1, 256,  0); GATHER_L(p2, 512,  0);
  GATHER_L(p3, 768,  0); GATHER_L(p4, 1024, 0); GATHER_L(p5, 1280, 0);
  GATHER_L(p6, 1536, 0); GATHER_L(p7, 1792, 0);

  // u_part[j] = b1[j] + u @ W1[0:128,:]
  {
    int j = tid & 15, g = tid >> 4;
    float p = 0.f;
#pragma unroll
    for (int t = 0; t < 8; ++t) {
      int d = g * 8 + t;
      p = fmaf(u_sh[d], W1[d * 16 + j], p);
    }
    part[tid] = p;
  }
  __syncthreads();
  if (tid < 16) {
    float s = b1[tid];
#pragma unroll
    for (int g = 0; g < 16; ++g) s += part[g * 16 + tid];
    upart_sh[tid] = s;
  }
  __syncthreads();

  const float b2v = b2[0];
  const float w2a = W2[4 * w + 0], w2b = W2[4 * w + 1];
  const float w2c = W2[4 * w + 2], w2d = W2[4 * w + 3];

  float pacc = 0.f;                               // per-thread sum of unnorm weights
  float4 uacc = make_float4(0.f, 0.f, 0.f, 0.f);  // partial of sum_l p_l * e_l[4c..4c+3]

  // ================= stage 1: chunks 0..2 (cnt=64), fully unrolled =================
#pragma unroll
  for (int c = 0; c < 3; ++c) {
    const int base = c * CH;

    // -- stage prefetched rows: one ds_write_b128 each --
    STORE_L(p0, 0);    STORE_L(p1, 256);  STORE_L(p2, 512);  STORE_L(p3, 768);
    STORE_L(p4, 1024); STORE_L(p5, 1280); STORE_L(p6, 1536); STORE_L(p7, 1792);
    __syncthreads();

    MATVEC_PHASE(64);
    __syncthreads();

    // -- finalize logits -> unnormalized weights (no max-shift: |lg| << 80) --
    if (tid < 64) {
      float lg = hspart[tid] + hspart[65 + tid] + hspart[130 + tid] +
                 hspart[195 + tid] + b2v;
      float p = (rows1[base + tid] >= 0) ? expf(lg) : 0.f;
      w_sh[tid] = p;
      pacc += p;
    }
    __syncthreads();

    // -- prefetch next chunk (c<2) or tail + S rows (c==2): hides under accum --
    if (c < 2) {
      GATHER_L(p0, 0,    base + CH); GATHER_L(p1, 256,  base + CH);
      GATHER_L(p2, 512,  base + CH); GATHER_L(p3, 768,  base + CH);
      GATHER_L(p4, 1024, base + CH); GATHER_L(p5, 1280, base + CH);
      GATHER_L(p6, 1536, base + CH); GATHER_L(p7, 1792, base + CH);
    } else {
      GATHER_L(p0, 0, 192);          // tail chunk: 8 rows = 256 slots, p0 only
      GATHER_S(p1, 0);    GATHER_S(p2, 256);  GATHER_S(p3, 512);
      GATHER_S(p4, 768);  GATHER_S(p5, 1024); GATHER_S(p6, 1280);
      if (tid < 64) GATHER_S(p7, 1536);  // slots 1536..1599
    }

    // -- weighted accumulate: b128 reads, 8 row-groups x 32 float4-columns --
#pragma unroll
    for (int l8 = 0; l8 < 8; ++l8) {
      int l = grp + l8 * 8;
      float wl = w_sh[l];
      const float4 e = reinterpret_cast<const float4*>(&ebuf[l * ESTR])[col4];
      uacc.x = fmaf(wl, e.x, uacc.x);
      uacc.y = fmaf(wl, e.y, uacc.y);
      uacc.z = fmaf(wl, e.z, uacc.z);
      uacc.w = fmaf(wl, e.w, uacc.w);
    }
    __syncthreads();  // ebuf/w_sh reused next chunk
  }

  // ================= stage 1 tail: chunk 3 (rows 192..199 -> ebuf rows 0..7) ========
  STORE_L(p0, 0);
  __syncthreads();
  MATVEC_PHASE(8);
  __syncthreads();
  if (tid < 8) {
    float lg = hspart[tid] + hspart[65 + tid] + hspart[130 + tid] +
               hspart[195 + tid] + b2v;
    float p = (rows1[192 + tid] >= 0) ? expf(lg) : 0.f;
    w_sh[tid] = p;
    pacc += p;
  }
  __syncthreads();
  {  // single row per thread-group (l = grp < 8)
    float wl = w_sh[grp];
    const float4 e = reinterpret_cast<const float4*>(&ebuf[grp * ESTR])[col4];
    uacc.x = fmaf(wl, e.x, uacc.x);
    uacc.y = fmaf(wl, e.y, uacc.y);
    uacc.z = fmaf(wl, e.z, uacc.z);
    uacc.w = fmaf(wl, e.w, uacc.w);
  }

  // ---- u_long: reduce uacc (scratch = dead rows 52..63), normalize -> ebuf row 0 ----
  const float invS1 = 1.f / block_sum(pacc, red_sh);  // barriers protect ebuf reuse
  float* scr = &ebuf[52 * ESTR];  // 1024-float scratch; stage-2 rows end at 6728 < 6864
  reinterpret_cast<float4*>(scr)[tid] = uacc;         // scr[grp*128 + 4*col4 ..]
  __syncthreads();
  if (tid < D) {
    float s = 0.f;
#pragma unroll
    for (int g = 0; g < 8; ++g) s += scr[g * 128 + tid];
    ebuf[tid] = s * invS1;  // row 0 = u_long (stage-2 item 0)
  }
  // S rows (prefetched in p1..p7) -> ebuf rows 1..50 (disjoint from row 0 and scr)
  STORE_S(p1, 0);    STORE_S(p2, 256);  STORE_S(p3, 512);
  STORE_S(p4, 768);  STORE_S(p5, 1024); STORE_S(p6, 1280);
  if (tid < 64) STORE_S(p7, 1536);
  __syncthreads();

  // ================= stage 2: [u_long] + 50 S rows =================
  const int n2 = 1 + SLEN;  // 51
  MATVEC_PHASE(n2);
  __syncthreads();

  float p2v = 0.f;
  if (tid < n2) {
    float lg = hspart[tid] + hspart[65 + tid] + hspart[130 + tid] +
               hspart[195 + tid] + b2v;
    bool valid = (tid == 0) || (rowsS[tid - 1] >= 0);
    p2v = valid ? expf(lg) : 0.f;
    w_sh[tid] = p2v;
  }
  const float invS2 = 1.f / block_sum(p2v, red_sh);  // barrier publishes w_sh

  float4 uacc2 = make_float4(0.f, 0.f, 0.f, 0.f);
  for (int l = grp; l < n2; l += 8) {
    float wl = w_sh[l];
    const float4 e = reinterpret_cast<const float4*>(&ebuf[l * ESTR])[col4];
    uacc2.x = fmaf(wl, e.x, uacc2.x);
    uacc2.y = fmaf(wl, e.y, uacc2.y);
    uacc2.z = fmaf(wl, e.z, uacc2.z);
    uacc2.w = fmaf(wl, e.w, uacc2.w);
  }
  reinterpret_cast<float4*>(scr)[tid] = uacc2;  // rows 52..63 untouched by stage 2
  __syncthreads();

  // ---- score = dot(user_hybrid, item_emb) ----
  float sv = 0.f;
  if (tid < D) {
    float s = 0.f;
#pragma unroll
    for (int g = 0; g < 8; ++g) s += scr[g * 128 + tid];
    float uh = s * invS2;
    sv = uh * item_table[(size_t)item_inputs[b] * D + tid];
  }
  float tot = block_sum(sv, red_sh);
  if (tid == 0) out[b] = tot;
}

extern "C" void kernel_launch(void* const* d_in, const int* in_sizes, int n_in,
                              void* d_out, int out_size, void* d_ws, size_t ws_size,
                              hipStream_t stream) {
  const float* user_table = (const float*)d_in[0];
  const float* item_table = (const float*)d_in[1];
  const float* W1 = (const float*)d_in[2];
  const float* b1 = (const float*)d_in[3];
  const float* W2 = (const float*)d_in[4];
  const float* b2 = (const float*)d_in[5];
  const int* user_inputs = (const int*)d_in[6];
  const int* L_inputs = (const int*)d_in[7];
  const int* S_inputs = (const int*)d_in[8];
  const int* item_inputs = (const int*)d_in[9];
  float* out = (float*)d_out;

  const int B = in_sizes[6];  // 4096
  din_kernel<<<B, 256, 0, stream>>>(user_table, item_table, W1, b1, W2, b2,
                                    user_inputs, L_inputs, S_inputs, item_inputs,
                                    out);
}

// Round 3
// 256.537 us; speedup vs baseline: 1.8493x; 1.0507x over previous
//
#include <hip/hip_runtime.h>
#include <math.h>

#define D 128
#define LLEN 200
#define SLEN 50
#define CH 56    // 56*132*4 = 29,568B tile -> total LDS ~31.9KB -> 5 blocks/CU
#define ESTR 132 // floats/row: 528B, 16B-aligned; b128 quad = (33r+c4)&7 = (r+c4)&7 -> conflict-free

__device__ __forceinline__ float wave_red_sum(float v) {
#pragma unroll
  for (int m = 32; m >= 1; m >>= 1) v += __shfl_xor(v, m, 64);
  return v;
}
// 256-thread block sum; ALL threads must call.
__device__ __forceinline__ float block_sum(float v, float* red) {
  v = wave_red_sum(v);
  if ((threadIdx.x & 63) == 0) red[threadIdx.x >> 6] = v;
  __syncthreads();
  v = red[0] + red[1] + red[2] + red[3];
  __syncthreads();
  return v;
}

// Unconditional gathers/stores: caller guarantees slot validity.
#define GATHER_L(dst, IT, BASE)                        \
  do {                                                 \
    int s_ = tid + (IT);                               \
    int gid_ = rows1[(BASE) + (s_ >> 5)];              \
    if (gid_ < 0) gid_ = 0;                            \
    dst = it4[(size_t)gid_ * 32 + (s_ & 31)];          \
  } while (0)

#define GATHER_S(dst, IT)                              \
  do {                                                 \
    int s_ = tid + (IT);                               \
    int gid_ = rowsS[s_ >> 5];                         \
    if (gid_ < 0) gid_ = 0;                            \
    dst = it4[(size_t)gid_ * 32 + (s_ & 31)];          \
  } while (0)

#define STORE_L(src, IT)                                                     \
  do {                                                                       \
    int s_ = tid + (IT);                                                     \
    reinterpret_cast<float4*>(&ebuf[(s_ >> 5) * ESTR])[s_ & 31] = src;       \
  } while (0)

#define STORE_S(src, IT)                                                     \
  do {                                                                       \
    int s_ = tid + (IT);                                                     \
    reinterpret_cast<float4*>(&ebuf[((s_ >> 5) + 1) * ESTR])[s_ & 31] = src; \
  } while (0)

#define FMA4(WL, P, ACC)                \
  do {                                  \
    ACC.x = fmaf((WL), P.x, ACC.x);     \
    ACC.y = fmaf((WL), P.y, ACC.y);     \
    ACC.z = fmaf((WL), P.z, ACC.z);     \
  } while (0);                          \
  ACC.w = fmaf((WL), P.w, ACC.w)

// Wave w computes j in [4w,4w+4) for item=lane; 32x ds_read_b128 per lane.
#define MATVEC_HS(CNT)                                                      \
  if (lane < (CNT)) {                                                       \
    float a0 = 0.f, a1 = 0.f, a2 = 0.f, a3 = 0.f;                           \
    const float4* er4 = reinterpret_cast<const float4*>(&ebuf[lane * ESTR]);\
    const float* wc = &W1[(size_t)D * 16 + 4 * w];                          \
    _Pragma("unroll 8")                                                     \
    for (int k = 0; k < 32; ++k) {                                          \
      float4 e = er4[k];                                                    \
      const float* wr = wc + k * 64; /* wave-uniform -> s_load */           \
      a0 = fmaf(e.x, wr[0],  a0); a1 = fmaf(e.x, wr[1],  a1);               \
      a2 = fmaf(e.x, wr[2],  a2); a3 = fmaf(e.x, wr[3],  a3);               \
      a0 = fmaf(e.y, wr[16], a0); a1 = fmaf(e.y, wr[17], a1);               \
      a2 = fmaf(e.y, wr[18], a2); a3 = fmaf(e.y, wr[19], a3);               \
      a0 = fmaf(e.z, wr[32], a0); a1 = fmaf(e.z, wr[33], a1);               \
      a2 = fmaf(e.z, wr[34], a2); a3 = fmaf(e.z, wr[35], a3);               \
      a0 = fmaf(e.w, wr[48], a0); a1 = fmaf(e.w, wr[49], a1);               \
      a2 = fmaf(e.w, wr[50], a2); a3 = fmaf(e.w, wr[51], a3);               \
    }                                                                       \
    float hs = fmaxf(upart_sh[4 * w + 0] + a0, 0.f) * w2a;                  \
    hs = fmaf(fmaxf(upart_sh[4 * w + 1] + a1, 0.f), w2b, hs);               \
    hs = fmaf(fmaxf(upart_sh[4 * w + 2] + a2, 0.f), w2c, hs);               \
    hs = fmaf(fmaxf(upart_sh[4 * w + 3] + a3, 0.f), w2d, hs);               \
    hspart[w * 65 + lane] = hs;                                             \
  }

// Finalize: logits -> unnormalized weights (no max-shift: |lg| << 80).
#define FINALIZE_L(CNT, BASE)                                           \
  if (tid < (CNT)) {                                                    \
    float lg = hspart[tid] + hspart[65 + tid] + hspart[130 + tid] +     \
               hspart[195 + tid] + b2v;                                 \
    float p_ = (rows1[(BASE) + tid] >= 0) ? expf(lg) : 0.f;             \
    w_sh[tid] = p_;                                                     \
    pacc += p_;                                                         \
  }

__global__ void __launch_bounds__(256, 5) din_kernel(
    const float* __restrict__ user_table, const float* __restrict__ item_table,
    const float* __restrict__ W1, const float* __restrict__ b1,
    const float* __restrict__ W2, const float* __restrict__ b2,
    const int* __restrict__ user_inputs, const int* __restrict__ L_inputs,
    const int* __restrict__ S_inputs, const int* __restrict__ item_inputs,
    float* __restrict__ out) {
  __shared__ float ebuf[CH * ESTR];   // 29,568B staged rows; also prolog/epilog scratch
  __shared__ float hspart[4 * 65];    // per-wave hs partials, stride 65
  __shared__ float w_sh[CH];          // unnormalized softmax weights for current chunk
  __shared__ int rows1[LLEN];
  __shared__ int rowsS[SLEN];
  __shared__ float upart_sh[16];
  __shared__ float red_sh[4];

  const int b = blockIdx.x;
  const int tid = threadIdx.x;
  const int lane = tid & 63;
  const int w = __builtin_amdgcn_readfirstlane(tid >> 6);  // wave id -> SGPR
  const int col4 = tid & 31;          // float4 column (d = 4*col4..+3)
  const int grp = tid >> 5;           // row group 0..7
  const float4* it4 = reinterpret_cast<const float4*>(item_table);

  // ---- prolog: indices + user embedding + item embedding prefetch ----
  float* u_sh = &ebuf[0];
  float* part = &ebuf[128];
  if (tid < D) u_sh[tid] = user_table[(size_t)user_inputs[b] * D + tid];
  const float item_f =
      (tid < D) ? item_table[(size_t)item_inputs[b] * D + tid] : 0.f;
  if (tid < LLEN) rows1[tid] = L_inputs[(size_t)b * LLEN + tid];
  if (tid < SLEN) rowsS[tid] = S_inputs[(size_t)b * SLEN + tid];
  __syncthreads();

  // prefetch chunk 0 (56 rows = 1792 slots = 7 x 256): hides under prolog MLP
  float4 A0, A1, A2, A3, A4, A5, A6, B0, B1, B2, B3, B4, B5, B6;
  GATHER_L(A0, 0, 0);    GATHER_L(A1, 256, 0);  GATHER_L(A2, 512, 0);
  GATHER_L(A3, 768, 0);  GATHER_L(A4, 1024, 0); GATHER_L(A5, 1280, 0);
  GATHER_L(A6, 1536, 0);

  // u_part[j] = b1[j] + u @ W1[0:128,:]
  {
    int j = tid & 15, g = tid >> 4;
    float p = 0.f;
#pragma unroll
    for (int t = 0; t < 8; ++t) {
      int d = g * 8 + t;
      p = fmaf(u_sh[d], W1[d * 16 + j], p);
    }
    part[tid] = p;
  }
  __syncthreads();
  if (tid < 16) {
    float s = b1[tid];
#pragma unroll
    for (int g = 0; g < 16; ++g) s += part[g * 16 + tid];
    upart_sh[tid] = s;
  }
  __syncthreads();

  const float b2v = b2[0];
  const float w2a = W2[4 * w + 0], w2b = W2[4 * w + 1];
  const float w2c = W2[4 * w + 2], w2d = W2[4 * w + 3];

  float pacc = 0.f;
  float4 uacc = make_float4(0.f, 0.f, 0.f, 0.f);
  float wl;

  // ================= chunk 0: base 0, regs A; prefetch B (chunk 1) =================
  STORE_L(A0, 0);    STORE_L(A1, 256);  STORE_L(A2, 512);  STORE_L(A3, 768);
  STORE_L(A4, 1024); STORE_L(A5, 1280); STORE_L(A6, 1536);
  __syncthreads();
  MATVEC_HS(56);
  GATHER_L(B0, 0, 56);    GATHER_L(B1, 256, 56);  GATHER_L(B2, 512, 56);
  GATHER_L(B3, 768, 56);  GATHER_L(B4, 1024, 56); GATHER_L(B5, 1280, 56);
  GATHER_L(B6, 1536, 56);
  __syncthreads();
  FINALIZE_L(56, 0);
  __syncthreads();
  wl = w_sh[grp];      FMA4(wl, A0, uacc);
  wl = w_sh[grp + 8];  FMA4(wl, A1, uacc);
  wl = w_sh[grp + 16]; FMA4(wl, A2, uacc);
  wl = w_sh[grp + 24]; FMA4(wl, A3, uacc);
  wl = w_sh[grp + 32]; FMA4(wl, A4, uacc);
  wl = w_sh[grp + 40]; FMA4(wl, A5, uacc);
  wl = w_sh[grp + 48]; FMA4(wl, A6, uacc);
  // no barrier: accum is reg/w_sh-read only; next stores touch ebuf; w_sh
  // rewritten only after two more barriers.

  // ================= chunk 1: base 56, regs B; prefetch A (chunk 2) =================
  STORE_L(B0, 0);    STORE_L(B1, 256);  STORE_L(B2, 512);  STORE_L(B3, 768);
  STORE_L(B4, 1024); STORE_L(B5, 1280); STORE_L(B6, 1536);
  __syncthreads();
  MATVEC_HS(56);
  GATHER_L(A0, 0, 112);    GATHER_L(A1, 256, 112);  GATHER_L(A2, 512, 112);
  GATHER_L(A3, 768, 112);  GATHER_L(A4, 1024, 112); GATHER_L(A5, 1280, 112);
  GATHER_L(A6, 1536, 112);
  __syncthreads();
  FINALIZE_L(56, 56);
  __syncthreads();
  wl = w_sh[grp];      FMA4(wl, B0, uacc);
  wl = w_sh[grp + 8];  FMA4(wl, B1, uacc);
  wl = w_sh[grp + 16]; FMA4(wl, B2, uacc);
  wl = w_sh[grp + 24]; FMA4(wl, B3, uacc);
  wl = w_sh[grp + 32]; FMA4(wl, B4, uacc);
  wl = w_sh[grp + 40]; FMA4(wl, B5, uacc);
  wl = w_sh[grp + 48]; FMA4(wl, B6, uacc);

  // ================= chunk 2: base 112, regs A; prefetch B0..B3 (tail) ==============
  STORE_L(A0, 0);    STORE_L(A1, 256);  STORE_L(A2, 512);  STORE_L(A3, 768);
  STORE_L(A4, 1024); STORE_L(A5, 1280); STORE_L(A6, 1536);
  __syncthreads();
  MATVEC_HS(56);
  GATHER_L(B0, 0, 168); GATHER_L(B1, 256, 168);
  GATHER_L(B2, 512, 168); GATHER_L(B3, 768, 168);
  __syncthreads();
  FINALIZE_L(56, 112);
  __syncthreads();
  wl = w_sh[grp];      FMA4(wl, A0, uacc);
  wl = w_sh[grp + 8];  FMA4(wl, A1, uacc);
  wl = w_sh[grp + 16]; FMA4(wl, A2, uacc);
  wl = w_sh[grp + 24]; FMA4(wl, A3, uacc);
  wl = w_sh[grp + 32]; FMA4(wl, A4, uacc);
  wl = w_sh[grp + 40]; FMA4(wl, A5, uacc);
  wl = w_sh[grp + 48]; FMA4(wl, A6, uacc);

  // ================= tail: base 168, 32 rows, regs B0..3; prefetch A = S rows =======
  STORE_L(B0, 0); STORE_L(B1, 256); STORE_L(B2, 512); STORE_L(B3, 768);
  __syncthreads();
  MATVEC_HS(32);
  GATHER_S(A0, 0);    GATHER_S(A1, 256);  GATHER_S(A2, 512);
  GATHER_S(A3, 768);  GATHER_S(A4, 1024); GATHER_S(A5, 1280);
  if (tid < 64) GATHER_S(A6, 1536);
  __syncthreads();
  FINALIZE_L(32, 168);
  __syncthreads();
  wl = w_sh[grp];      FMA4(wl, B0, uacc);
  wl = w_sh[grp + 8];  FMA4(wl, B1, uacc);
  wl = w_sh[grp + 16]; FMA4(wl, B2, uacc);
  wl = w_sh[grp + 24]; FMA4(wl, B3, uacc);

  // ---- u_long: block_sum(pacc), in-wave grp-pair combine, scr = dead rows 52..55 ----
  const float invS1 = 1.f / block_sum(pacc, red_sh);
  uacc.x += __shfl_xor(uacc.x, 32, 64);
  uacc.y += __shfl_xor(uacc.y, 32, 64);
  uacc.z += __shfl_xor(uacc.z, 32, 64);
  uacc.w += __shfl_xor(uacc.w, 32, 64);
  float* scr = &ebuf[52 * ESTR];  // 512-float scratch (rows 52..55, 528 floats)
  if (lane < 32) reinterpret_cast<float4*>(scr)[(w << 5) + lane] = uacc;
  // S rows (prefetched in A) -> ebuf rows 1..50 (disjoint from row 0 and scr)
  STORE_S(A0, 0);    STORE_S(A1, 256);  STORE_S(A2, 512);
  STORE_S(A3, 768);  STORE_S(A4, 1024); STORE_S(A5, 1280);
  if (tid < 64) STORE_S(A6, 1536);
  __syncthreads();
  if (tid < D) {
    float s = scr[tid] + scr[128 + tid] + scr[256 + tid] + scr[384 + tid];
    ebuf[tid] = s * invS1;  // row 0 = u_long (stage-2 item 0)
  }
  __syncthreads();

  // ================= stage 2: [u_long] + 50 S rows (rows 0..50) =================
  MATVEC_HS(51);
  __syncthreads();
  float pacc2 = 0.f;
  if (tid < 51) {
    float lg = hspart[tid] + hspart[65 + tid] + hspart[130 + tid] +
               hspart[195 + tid] + b2v;
    bool valid = (tid == 0) || (rowsS[tid - 1] >= 0);
    float p_ = valid ? expf(lg) : 0.f;
    w_sh[tid] = p_;
    pacc2 = p_;
  }
  __syncthreads();

  float4 uacc2 = make_float4(0.f, 0.f, 0.f, 0.f);
  if (grp == 0) {  // seq position 0 = u_long, staged only in LDS row 0
    float wl0 = w_sh[0];
    const float4 e = reinterpret_cast<const float4*>(&ebuf[0])[col4];
    FMA4(wl0, e, uacc2);
  }
  // S rows from regs: reg A_it holds S-row grp+8*it at col4 -> seq pos 1+grp+8*it
  wl = w_sh[1 + grp];      FMA4(wl, A0, uacc2);
  wl = w_sh[1 + grp + 8];  FMA4(wl, A1, uacc2);
  wl = w_sh[1 + grp + 16]; FMA4(wl, A2, uacc2);
  wl = w_sh[1 + grp + 24]; FMA4(wl, A3, uacc2);
  wl = w_sh[1 + grp + 32]; FMA4(wl, A4, uacc2);
  wl = w_sh[1 + grp + 40]; FMA4(wl, A5, uacc2);
  if (grp < 2) { wl = w_sh[1 + grp + 48]; FMA4(wl, A6, uacc2); }

  const float invS2 = 1.f / block_sum(pacc2, red_sh);
  uacc2.x += __shfl_xor(uacc2.x, 32, 64);
  uacc2.y += __shfl_xor(uacc2.y, 32, 64);
  uacc2.z += __shfl_xor(uacc2.z, 32, 64);
  uacc2.w += __shfl_xor(uacc2.w, 32, 64);
  if (lane < 32) reinterpret_cast<float4*>(scr)[(w << 5) + lane] = uacc2;
  __syncthreads();

  // ---- score = dot(user_hybrid, item_emb) ----
  float sv = 0.f;
  if (tid < D) {
    float s = scr[tid] + scr[128 + tid] + scr[256 + tid] + scr[384 + tid];
    sv = s * invS2 * item_f;
  }
  float tot = block_sum(sv, red_sh);
  if (tid == 0) out[b] = tot;
}

extern "C" void kernel_launch(void* const* d_in, const int* in_sizes, int n_in,
                              void* d_out, int out_size, void* d_ws, size_t ws_size,
                              hipStream_t stream) {
  const float* user_table = (const float*)d_in[0];
  const float* item_table = (const float*)d_in[1];
  const float* W1 = (const float*)d_in[2];
  const float* b1 = (const float*)d_in[3];
  const float* W2 = (const float*)d_in[4];
  const float* b2 = (const float*)d_in[5];
  const int* user_inputs = (const int*)d_in[6];
  const int* L_inputs = (const int*)d_in[7];
  const int* S_inputs = (const int*)d_in[8];
  const int* item_inputs = (const int*)d_in[9];
  float* out = (float*)d_out;

  const int B = in_sizes[6];  // 4096
  din_kernel<<<B, 256, 0, stream>>>(user_table, item_table, W1, b1, W2, b2,
                                    user_inputs, L_inputs, S_inputs, item_inputs,
                                    out);
}